// Round 8
// baseline (217.183 us; speedup 1.0000x reference)
//
#include <hip/hip_runtime.h>
#include <stdint.h>

// Problem constants: B=4, S=4096, E=256
#define SEQ   4096
#define EMB   256
#define NROW  16384   // B*S

typedef short s16x8  __attribute__((ext_vector_type(8)));
typedef float f32x4  __attribute__((ext_vector_type(4)));
typedef float f32x16 __attribute__((ext_vector_type(16)));
typedef unsigned int u32;

#define LOG2E 1.44269504088896340736f
#define RESCALE_THR 8.0f

__device__ __forceinline__ unsigned short f2bf(float f) {
    unsigned int u = __builtin_bit_cast(unsigned int, f);
    u += 0x7FFFu + ((u >> 16) & 1u);   // RNE
    return (unsigned short)(u >> 16);
}

__device__ __forceinline__ u32 pkbf2(float lo, float hi) {
    return (u32)f2bf(lo) | ((u32)f2bf(hi) << 16);
}

// global -> LDS direct (16B per lane, linear dest).  AS(3) ptr is 32-bit; the
// uintptr_t truncation keeps the LDS offset (addrspacecast lowering puts the
// aperture in the high 32 bits only).
typedef __attribute__((address_space(3))) u32 lds_u32;
typedef __attribute__((address_space(1))) const u32 glb_u32;
__device__ __forceinline__ void gload16(const unsigned short* g, const unsigned short* l) {
    __builtin_amdgcn_global_load_lds((glb_u32*)(uintptr_t)g,
                                     (lds_u32*)(u32)(uintptr_t)l, 16, 0, 0);
}

// ---------------------------------------------------------------------------
// Kernel 0: convert x and Wq/Wk/Wv fp32 -> bf16 once.
// ---------------------------------------------------------------------------
__global__ __launch_bounds__(256, 8) void xcvt_kernel(
    const float* __restrict__ x, const float* __restrict__ Wq,
    const float* __restrict__ Wk, const float* __restrict__ Wv,
    unsigned short* __restrict__ xb, unsigned short* __restrict__ Wb)
{
    const int gid = blockIdx.x*256 + threadIdx.x;
    const float* src;
    unsigned short* dst;
    size_t off;
    if (gid < 524288) {                 // x: 4,194,304 elems
        src = x; dst = xb; off = (size_t)gid * 8;
    } else {                            // W: 3 x 65,536 elems
        size_t wi = (size_t)(gid - 524288) * 8;
        int w = (int)(wi >> 16);
        off = wi & 65535;
        src = (w == 0) ? Wq : (w == 1) ? Wk : Wv;
        dst = Wb + (size_t)w * 65536;
    }
    const float4 v0 = *(const float4*)(src + off);
    const float4 v1 = *(const float4*)(src + off + 4);
    union { unsigned short u[8]; s16x8 v; } o;
    o.u[0]=f2bf(v0.x); o.u[1]=f2bf(v0.y); o.u[2]=f2bf(v0.z); o.u[3]=f2bf(v0.w);
    o.u[4]=f2bf(v1.x); o.u[5]=f2bf(v1.y); o.u[6]=f2bf(v1.z); o.u[7]=f2bf(v1.w);
    *(s16x8*)(dst + off) = o.v;
}

// ---------------------------------------------------------------------------
// Kernel 1: QKV projection (bf16 in, bf16 out).  Grid 512 = 8 col-tiles(32) x
// 64 row-groups(256); 2 blocks/CU.  Q/K stores staged via LDS -> b128 stores.
// ---------------------------------------------------------------------------
#define PWSTR 264

__global__ __launch_bounds__(256, 2) void proj_kernel(
    const unsigned short* __restrict__ xb, const unsigned short* __restrict__ Wb,
    unsigned short* __restrict__ Qb, unsigned short* __restrict__ Kb,
    unsigned short* __restrict__ Vt)
{
    __shared__ unsigned short Wl[3][32][PWSTR];  // 50688 B
    __shared__ unsigned short QKs[2][64][40];    // 10240 B
    __shared__ unsigned short Vtr[32][72];       //  4608 B   (total 65536 B)
    const int bid = blockIdx.x;
    const int ct  = bid >> 6;   // 0..7: 32 out-cols
    const int rb  = bid & 63;   // 256-row group
    const int t   = threadIdx.x;

    {   // stage 32x256 bf16 chunk of each W (plain b128 copies)
        const int o = t >> 3, seg = t & 7;
        #pragma unroll
        for (int w = 0; w < 3; ++w) {
            const unsigned short* src = Wb + (size_t)w*65536 + (ct*32 + o)*256 + seg*32;
            #pragma unroll
            for (int i = 0; i < 4; ++i)
                *(s16x8*)&Wl[w][o][seg*32 + i*8] = *(const s16x8*)(src + i*8);
        }
    }
    __syncthreads();

    const int wave = t >> 6, lane = t & 63;
    const int g = lane >> 4, lr = lane & 15;

    for (int it = 0; it < 4; ++it) {
        const int rowblk = rb*256 + it*64;
        const int rowbase = rowblk + wave*16;
        s16x8 a[8];
        {
            const unsigned short* xr = xb + (size_t)(rowbase + lr)*256;
            #pragma unroll
            for (int c = 0; c < 8; ++c)
                a[c] = *(const s16x8*)(xr + c*32 + g*8);
        }
        f32x4 acc[3][2];
        #pragma unroll
        for (int w = 0; w < 3; ++w)
            #pragma unroll
            for (int cf = 0; cf < 2; ++cf)
                #pragma unroll
                for (int j = 0; j < 4; ++j) acc[w][cf][j] = 0.0f;

        #pragma unroll
        for (int w = 0; w < 3; ++w)
            #pragma unroll
            for (int cf = 0; cf < 2; ++cf)
                #pragma unroll
                for (int c = 0; c < 8; ++c) {
                    s16x8 bfr = *(const s16x8*)&Wl[w][cf*16 + lr][c*32 + g*8];
                    acc[w][cf] = __builtin_amdgcn_mfma_f32_16x16x32_bf16(a[c], bfr, acc[w][cf], 0, 0, 0);
                }

        __syncthreads();   // prev iteration's staging reads done
        #pragma unroll
        for (int cf = 0; cf < 2; ++cf) {
            #pragma unroll
            for (int j = 0; j < 4; ++j) {
                const int row = wave*16 + g*4 + j;
                QKs[0][row][cf*16 + lr] = f2bf(acc[0][cf][j] * 0.0625f);  // fold 1/sqrt(256)
                QKs[1][row][cf*16 + lr] = f2bf(acc[1][cf][j]);
            }
            ushort4 pv;
            pv.x = f2bf(acc[2][cf][0]); pv.y = f2bf(acc[2][cf][1]);
            pv.z = f2bf(acc[2][cf][2]); pv.w = f2bf(acc[2][cf][3]);
            *(ushort4*)&Vtr[cf*16 + lr][wave*16 + g*4] = pv;
        }
        __syncthreads();
        {   // coalesced b128 stores
            const int row = t >> 2, cs = t & 3;
            *(s16x8*)&Qb[(size_t)(rowblk + row)*256 + ct*32 + cs*8] = *(const s16x8*)&QKs[0][row][cs*8];
            *(s16x8*)&Kb[(size_t)(rowblk + row)*256 + ct*32 + cs*8] = *(const s16x8*)&QKs[1][row][cs*8];
            const int colL = t >> 3, seg = t & 7;
            const int bb = rowblk >> 12, ss0 = rowblk & 4095;
            *(s16x8*)&Vt[((size_t)(bb*256 + ct*32 + colL))*4096 + ss0 + seg*8] = *(const s16x8*)&Vtr[colL][seg*8];
        }
    }
}

// ---------------------------------------------------------------------------
// Kernel 2: flash attention.  Grid 256 = 8 (b,h) XCD-pinned groups x 32
// q-tiles(128).  512 threads = 8 waves: (qh 0..3) x (kvh 0..1).  Each wave:
// 32 q-rows x its 32-kv half of each KVB=64 tile, 32x32x16 MFMA, swapped QK^T.
// global_load_lds staging (pre-swizzled source, XOR slot^=row&7), double-buffered.
// In-register P redistribution via shfl_xor(32).  kv-halves merged in-block;
// h=0 partial -> ws, h=1 -> out; combine kernel finishes.
// ---------------------------------------------------------------------------
#define AKVB 64
#define ANT  32          // 2048 kv per block / 64

__global__ __launch_bounds__(512, 2) void attn_kernel(
    const unsigned short* __restrict__ Qb, const unsigned short* __restrict__ Kb,
    const unsigned short* __restrict__ Vt, float* __restrict__ pacc0,
    float* __restrict__ pm, float* __restrict__ pl, float* __restrict__ out)
{
    __shared__ unsigned short KV[65536];   // K: [2][64][256] @0 ; V: [2][256][64] @32768 (elems)
    __shared__ float All[8][32];
    __shared__ float MrgM[128], MrgL[128], Wt1[128], Wt2[128];

    const int bid = blockIdx.x;
    const int grp = bid & 7;                 // XCD pin
    const int b = grp >> 1, h = grp & 1;
    const int qt = bid >> 3;
    const int t = threadIdx.x;
    const int w = t >> 6, lane = t & 63;
    const int h8 = lane >> 5, lr5 = lane & 31;
    const int qh = w >> 1, kvh = w & 1;
    const int kv0 = h * 2048;
    const int rowbase = b*4096 + qt*128 + qh*32;

    const unsigned short* Kg = Kb + (size_t)b*4096*256;
    const unsigned short* Vg = Vt + (size_t)b*256*4096;

    // Q B-fragments: col = q = lr5, k = mi*16 + h8*8 + j
    s16x8 qa[16];
    {
        const unsigned short* qp = Qb + (size_t)(rowbase + lr5)*256;
        #pragma unroll
        for (int mi = 0; mi < 16; ++mi)
            qa[mi] = *(const s16x8*)(qp + mi*16 + h8*8);
    }

    f32x16 acc[8];
    #pragma unroll
    for (int cc = 0; cc < 8; ++cc)
        #pragma unroll
        for (int r = 0; r < 16; ++r) acc[cc][r] = 0.0f;
    float m = -__builtin_inff(), l = 0.0f;   // per-lane state for q = lr5

    auto stage = [&](int buf, int kt2) {
        const int kvb = kv0 + kt2*AKVB;
        #pragma unroll
        for (int i = 0; i < 4; ++i) {
            const int idx = i*512 + t;
            const int kr = idx >> 5, ks = idx & 31;          // K: 64 rows x 32 slots
            gload16(Kg + (size_t)(kvb + kr)*256 + ((ks ^ (kr & 7)) << 3),
                    &KV[buf*16384 + (idx << 3)]);
            const int vr = idx >> 3, vs = idx & 7;           // V: 256 rows x 8 slots
            gload16(Vg + (size_t)vr*4096 + kvb + ((vs ^ (vr & 7)) << 3),
                    &KV[32768 + buf*16384 + (idx << 3)]);
        }
    };

    stage(0, 0);

    for (int kt = 0; kt < ANT; ++kt) {
        const int buf = kt & 1;
        __asm__ volatile("s_waitcnt vmcnt(0)" ::: "memory");
        __builtin_amdgcn_s_barrier();
        if (kt + 1 < ANT) stage(buf ^ 1, kt + 1);

        // Swapped QK^T (32x32x16): A = K rows (row = kv_local = lr5 in this
        // wave's half), B = Q.  C: col = q = lr5, row = kv = (r&3)+8*(r>>2)+4*h8.
        const int krow = kvh*32 + lr5;
        const int kbase = buf*16384 + krow*256;
        const int ksw = krow & 7;
        f32x16 sc;
        #pragma unroll
        for (int r = 0; r < 16; ++r) sc[r] = 0.0f;
        __builtin_amdgcn_s_setprio(1);
        #pragma unroll
        for (int mi = 0; mi < 16; ++mi) {
            const int slot = (2*mi + h8) ^ ksw;
            s16x8 kf = *(const s16x8*)&KV[kbase + slot*8];
            sc = __builtin_amdgcn_mfma_f32_32x32x16_bf16(kf, qa[mi], sc, 0, 0, 0);
        }
        __builtin_amdgcn_s_setprio(0);

        // row-max for q=lr5: 15 in-lane + 1 shfl
        float pmax = sc[0];
        #pragma unroll
        for (int r = 1; r < 16; ++r) pmax = fmaxf(pmax, sc[r]);
        pmax = fmaxf(pmax, __shfl_xor(pmax, 32));

        if (!__all(pmax - m <= RESCALE_THR)) {
            const float mn = fmaxf(m, pmax);
            const float al = __builtin_amdgcn_exp2f((m - mn) * LOG2E);
            m = mn; l *= al;
            if (lane < 32) All[w][lr5] = al;     // bridge to C-row layout
            #pragma unroll
            for (int rr = 0; rr < 4; ++rr) {
                f32x4 a4 = *(const f32x4*)&All[w][rr*8 + 4*h8];
                #pragma unroll
                for (int rj = 0; rj < 4; ++rj)
                    #pragma unroll
                    for (int cc = 0; cc < 8; ++cc) acc[cc][rr*4 + rj] *= a4[rj];
            }
        }

        // P = exp2((S-m)*log2e) in place; row-sum
        #pragma unroll
        for (int r = 0; r < 16; ++r) sc[r] = __builtin_amdgcn_exp2f((sc[r] - m) * LOG2E);
        float ps = ((sc[0]+sc[1]) + (sc[2]+sc[3])) + ((sc[4]+sc[5]) + (sc[6]+sc[7]))
                 + ((sc[8]+sc[9]) + (sc[10]+sc[11])) + ((sc[12]+sc[13]) + (sc[14]+sc[15]));
        ps += __shfl_xor(ps, 32);
        l += ps;

        // P -> A-fragments (row=q=lr5, k=kv) fully in-register:
        // dw[t] packs kv pair ((2e)+8t+4h8, +1); half-exchange via shfl_xor 32.
        const u32 dw0 = pkbf2(sc[0],  sc[1]),  dw1 = pkbf2(sc[2],  sc[3]);
        const u32 dw2 = pkbf2(sc[4],  sc[5]),  dw3 = pkbf2(sc[6],  sc[7]);
        const u32 dw4 = pkbf2(sc[8],  sc[9]),  dw5 = pkbf2(sc[10], sc[11]);
        const u32 dw6 = pkbf2(sc[12], sc[13]), dw7 = pkbf2(sc[14], sc[15]);
        const bool hi = (h8 != 0);
        const u32 s10 = __shfl_xor(hi ? dw0 : dw2, 32);
        const u32 s11 = __shfl_xor(hi ? dw1 : dw3, 32);
        const u32 s20 = __shfl_xor(hi ? dw4 : dw6, 32);
        const u32 s21 = __shfl_xor(hi ? dw5 : dw7, 32);
        union { u32 u[4]; s16x8 v; } pa1, pa2;
        pa1.u[0] = hi ? s10 : dw0;  pa1.u[1] = hi ? s11 : dw1;
        pa1.u[2] = hi ? dw2 : s10;  pa1.u[3] = hi ? dw3 : s11;
        pa2.u[0] = hi ? s20 : dw4;  pa2.u[1] = hi ? s21 : dw5;
        pa2.u[2] = hi ? dw6 : s20;  pa2.u[3] = hi ? dw7 : s21;

        // PV: out[32q][256d] += P[32q x 32kv] * V[32kv x d]
        const int vb0 = 32768 + buf*16384;
        __builtin_amdgcn_s_setprio(1);
        #pragma unroll
        for (int cc = 0; cc < 8; ++cc) {
            const int vrow = cc*32 + lr5;
            const int vsw = vrow & 7;
            s16x8 v1 = *(const s16x8*)&KV[vb0 + vrow*64 + (((4*kvh + h8)     ^ vsw) << 3)];
            s16x8 v2 = *(const s16x8*)&KV[vb0 + vrow*64 + (((4*kvh + 2 + h8) ^ vsw) << 3)];
            acc[cc] = __builtin_amdgcn_mfma_f32_32x32x16_bf16(pa1.v, v1, acc[cc], 0, 0, 0);
            acc[cc] = __builtin_amdgcn_mfma_f32_32x32x16_bf16(pa2.v, v2, acc[cc], 0, 0, 0);
        }
        __builtin_amdgcn_s_setprio(0);
    }

    // ---- in-block merge of the two kv-halves (reuse KV LDS as fp32 scratch) ----
    __syncthreads();
    float* Mrg = (float*)&KV[0];   // 32768 floats = [4 qh][32 q][256 d]
    if (kvh) {
        #pragma unroll
        for (int cc = 0; cc < 8; ++cc)
            #pragma unroll
            for (int r = 0; r < 16; ++r) {
                const int qr = (r & 3) + 8*(r >> 2) + 4*h8;
                Mrg[(qh*32 + qr)*256 + cc*32 + lr5] = acc[cc][r];
            }
        if (lane < 32) { MrgM[qh*32 + lr5] = m; MrgL[qh*32 + lr5] = l; }
    }
    __syncthreads();
    if (!kvh) {
        const float m2 = MrgM[qh*32 + lr5], l2 = MrgL[qh*32 + lr5];
        const float M  = fmaxf(m, m2);
        const float w1 = __builtin_amdgcn_exp2f((m  - M) * LOG2E);
        const float w2 = __builtin_amdgcn_exp2f((m2 - M) * LOG2E);
        const float lo = l*w1 + l2*w2;
        if (lane < 32) {
            Wt1[qh*32 + lr5] = w1; Wt2[qh*32 + lr5] = w2;
            pm[h*NROW + rowbase + lr5] = M;
            pl[h*NROW + rowbase + lr5] = lo;
        }
        float* dst = h ? out : pacc0;
        #pragma unroll
        for (int rr = 0; rr < 4; ++rr) {
            f32x4 w1q = *(const f32x4*)&Wt1[qh*32 + rr*8 + 4*h8];
            f32x4 w2q = *(const f32x4*)&Wt2[qh*32 + rr*8 + 4*h8];
            #pragma unroll
            for (int rj = 0; rj < 4; ++rj) {
                const int qr = rj + 8*rr + 4*h8;
                #pragma unroll
                for (int cc = 0; cc < 8; ++cc) {
                    const float v = acc[cc][rr*4 + rj]*w1q[rj]
                                  + Mrg[(qh*32 + qr)*256 + cc*32 + lr5]*w2q[rj];
                    dst[(size_t)(rowbase + qr)*256 + cc*32 + lr5] = v;
                }
            }
        }
    }
}

// ---------------------------------------------------------------------------
// Kernel 3: combine the two KV-half partials.
// ---------------------------------------------------------------------------
__global__ __launch_bounds__(256, 4) void combine_kernel(
    const float* __restrict__ pacc0, const float* __restrict__ pm,
    const float* __restrict__ pl, float* __restrict__ out)
{
    const int idx = blockIdx.x*256 + threadIdx.x;
    const int row = idx >> 6, d4 = (idx & 63) << 2;
    const float m0 = pm[row], m1 = pm[NROW + row];
    const float l0 = pl[row], l1 = pl[NROW + row];
    const float M = fmaxf(m0, m1);
    const float w0 = __builtin_amdgcn_exp2f((m0 - M) * LOG2E);
    const float w1 = __builtin_amdgcn_exp2f((m1 - M) * LOG2E);
    const float r = 1.0f / (l0*w0 + l1*w1);
    const float4 a0 = *(const float4*)(pacc0 + (size_t)row*256 + d4);
    float4 a1 = *(const float4*)(out + (size_t)row*256 + d4);
    a1.x = (a0.x*w0 + a1.x*w1) * r;
    a1.y = (a0.y*w0 + a1.y*w1) * r;
    a1.z = (a0.z*w0 + a1.z*w1) * r;
    a1.w = (a0.w*w0 + a1.w*w1) * r;
    *(float4*)(out + (size_t)row*256 + d4) = a1;
}

// ---------------------------------------------------------------------------
extern "C" void kernel_launch(void* const* d_in, const int* in_sizes, int n_in,
                              void* d_out, int out_size, void* d_ws, size_t ws_size,
                              hipStream_t stream) {
    const float* x  = (const float*)d_in[0];
    const float* Wq = (const float*)d_in[1];
    const float* Wk = (const float*)d_in[2];
    const float* Wv = (const float*)d_in[3];

    unsigned short* Qb = (unsigned short*)d_ws;          // 8 MB
    unsigned short* Kb = Qb + (size_t)NROW*EMB;          // 8 MB
    unsigned short* Vt = Kb + (size_t)NROW*EMB;          // 8 MB, [b][d][s]
    float* pacc0 = (float*)(Vt + (size_t)NROW*EMB);      // 16.8 MB
    float* pm    = pacc0 + (size_t)NROW*EMB;             // 128 KB
    float* pl    = pm + 2*NROW;                          // 128 KB
    // xb (8.4MB) + Wb (0.4MB) alias pacc0 (dead after proj; pacc0 written by attn)
    unsigned short* xb = (unsigned short*)pacc0;
    unsigned short* Wb = xb + (size_t)NROW*EMB;

    xcvt_kernel<<<2144, 256, 0, stream>>>(x, Wq, Wk, Wv, xb, Wb);
    proj_kernel<<<512, 256, 0, stream>>>(xb, Wb, Qb, Kb, Vt);
    attn_kernel<<<256, 512, 0, stream>>>(Qb, Kb, Vt, pacc0, pm, pl, (float*)d_out);
    combine_kernel<<<4096, 256, 0, stream>>>(pacc0, pm, pl, (float*)d_out);
}